// Round 2
// baseline (169.531 us; speedup 1.0000x reference)
//
#include <hip/hip_runtime.h>
#include <hip/hip_bf16.h>
#include <stdint.h>

// SSMBlock: x -> silu(x Wg^T) -> s = xg Wsp^T -> scan(decay) -> out = states WcT^T + xg W2^T + b_out
// GEMMs: bf16 MFMA 16x16x32, C = A[M,K] * W[N,K]^T, K=512 fixed.
// R1: 64x128 tile (grid 4 blocks/CU), 3-buffer LDS, depth-2 prefetch, counted vmcnt(6).

typedef __bf16 bf16_t;
typedef bf16_t bf16x8 __attribute__((ext_vector_type(8)));
typedef bf16_t bf16x4 __attribute__((ext_vector_type(4)));
typedef float  f32x4  __attribute__((ext_vector_type(4)));

static __device__ __forceinline__ void async_copy16(bf16_t* lds, const bf16_t* g) {
    __builtin_amdgcn_global_load_lds((const __attribute__((address_space(1))) void*)g,
                                     (__attribute__((address_space(3))) void*)lds, 16, 0, 0);
}

// 64(M)x128(N) tile, BK=32, K=512 -> 16 steps/phase. 256 threads = 4 waves (2x2),
// wave-tile 32x64, frag 2x4. LDS k-sliced [c][row][8]: global_load_lds dest linear in
// lane order, ds_read_b128 per-16-lane-group contiguous 256B (0 bank conflicts).
// Prefetch: stage(ss+2) -> vmcnt(6) -> barrier -> compute(ss) -> barrier.
// MODE: 0 = f32 out (+bias), 1 = bf16 out (+bias), 2 = silu -> bf16 (+bias)
template <int MODE>
__global__ __launch_bounds__(256, 4) void gemm_bt(
    const bf16_t* __restrict__ A0, const bf16_t* __restrict__ W0,
    const bf16_t* __restrict__ A1, const bf16_t* __restrict__ W1,
    const float* __restrict__ bias, void* __restrict__ outp,
    int M, int Nw, int nph)
{
    constexpr int K = 512, NKS = 16;
    __shared__ bf16_t As[3][4 * 64 * 8];    // 12 KB
    __shared__ bf16_t Bs[3][4 * 128 * 8];   // 24 KB
    const int tid = threadIdx.x;
    const int tN = Nw >> 7;
    int bid = blockIdx.x;
    {   // XCD-chunked swizzle (all our grids are %8==0); A-panel neighbors share an XCD L2
        int nwg = gridDim.x;
        if ((nwg & 7) == 0) bid = (bid & 7) * (nwg >> 3) + (bid >> 3);
    }
    const int m0 = (bid / tN) << 6, n0 = (bid % tN) << 7;
    const int l = tid & 63, w = tid >> 6;
    const int wr = w >> 1, wc = w & 1;
    const int lr = l & 15, kc = l >> 4;
    const int total = nph * NKS;

    // pre-load bias (before any stage, so it never perturbs in-loop vmcnt counts)
    float bv[4];
    #pragma unroll
    for (int j = 0; j < 4; ++j)
        bv[j] = bias ? bias[n0 + wc * 64 + j * 16 + lr] : 0.f;

    auto stage = [&](int ss) {
        const int ssc = ss < total ? ss : total - 1;   // clamped dummy -> dead buffer
        const bf16_t* Ap = (ssc >= NKS) ? A1 : A0;
        const bf16_t* Wp = (ssc >= NKS) ? W1 : W0;
        const int k0 = (ssc & (NKS - 1)) << 5;
        const int bufi = ss % 3;
        // A: 256 chunks, 1/thread: chunk = w*64 + l -> c = w, row = l
        async_copy16(&As[bufi][(w * 64) * 8],
                     Ap + (size_t)(m0 + l) * K + k0 + w * 8);
        // B: 512 chunks, 2/thread: chunk q = j*256 + tid -> c = q>>7, row = q&127
        #pragma unroll
        for (int j = 0; j < 2; ++j) {
            const int q = j * 256 + tid;
            const int c = q >> 7, row = q & 127;
            async_copy16(&Bs[bufi][(j * 256 + w * 64) * 8],
                         Wp + (size_t)(n0 + row) * K + k0 + c * 8);
        }
    };

    f32x4 acc[2][4];
    const f32x4 z = {0.f, 0.f, 0.f, 0.f};
    #pragma unroll
    for (int i = 0; i < 2; ++i)
        #pragma unroll
        for (int j = 0; j < 4; ++j) acc[i][j] = z;

    stage(0);
    stage(1);
    for (int ss = 0; ss < total; ++ss) {
        stage(ss + 2);                       // 3 loads -> up to 9 outstanding
        // wait for step ss's 3 loads (6 newer may stay in flight), then sync
        asm volatile("s_waitcnt vmcnt(6)\n\ts_barrier" ::: "memory");
        const bf16_t* Ab = As[ss % 3];
        const bf16_t* Bb = Bs[ss % 3];
        bf16x8 a[2], b[4];
        #pragma unroll
        for (int i = 0; i < 2; ++i)
            a[i] = *(const bf16x8*)(Ab + (kc * 64 + wr * 32 + i * 16 + lr) * 8);
        #pragma unroll
        for (int j = 0; j < 4; ++j)
            b[j] = *(const bf16x8*)(Bb + (kc * 128 + wc * 64 + j * 16 + lr) * 8);
        #pragma unroll
        for (int i = 0; i < 2; ++i)
            #pragma unroll
            for (int j = 0; j < 4; ++j)
                acc[i][j] = __builtin_amdgcn_mfma_f32_16x16x32_bf16(a[i], b[j], acc[i][j], 0, 0, 0);
        // all waves done reading buf[ss%3] before iter ss+1 overwrites it
        asm volatile("s_barrier" ::: "memory");
    }

    // C/D layout: col = lane&15, row = (lane>>4)*4 + reg
    float*  outF = (float*)outp;
    bf16_t* outB = (bf16_t*)outp;
    #pragma unroll
    for (int i = 0; i < 2; ++i) {
        const int row = m0 + wr * 32 + i * 16 + kc * 4;
        #pragma unroll
        for (int j = 0; j < 4; ++j) {
            const int col = n0 + wc * 64 + j * 16 + lr;
            #pragma unroll
            for (int r = 0; r < 4; ++r) {
                float v = acc[i][j][r] + bv[j];
                size_t idx = (size_t)(row + r) * Nw + col;
                if (MODE == 0)      outF[idx] = v;
                else if (MODE == 1) outB[idx] = (bf16_t)v;
                else { float sv = v / (1.f + __expf(-v)); outB[idx] = (bf16_t)sv; }
            }
        }
    }
}

__global__ void prep_weights(const float* __restrict__ Wg, const float* __restrict__ Wsp,
                             const float* __restrict__ Wo, const float* __restrict__ Dp,
                             bf16_t* __restrict__ Wg_bf, bf16_t* __restrict__ Wsp_bf,
                             bf16_t* __restrict__ Wo_bf, bf16_t* __restrict__ W2_bf)
{
    int i = blockIdx.x * 256 + threadIdx.x;   // 512*512 threads
    Wg_bf[i]  = (bf16_t)Wg[i];
    Wsp_bf[i] = (bf16_t)Wsp[i];
    float wo  = Wo[i];
    Wo_bf[i]  = (bf16_t)wo;
    W2_bf[i]  = (bf16_t)(wo * Dp[i & 511]);   // W2[d',d] = W_out[d',d]*D[d]
}

__global__ void convert_x(const float4* __restrict__ x, bf16x4* __restrict__ xb)
{
    int i = blockIdx.x * 256 + threadIdx.x;
    float4 v = x[i];
    bf16x4 o;
    o[0] = (bf16_t)v.x; o[1] = (bf16_t)v.y; o[2] = (bf16_t)v.z; o[3] = (bf16_t)v.w;
    xb[i] = o;
}

__global__ void compute_decay(const float* __restrict__ A_log, float* __restrict__ decay)
{
    int d = blockIdx.x * 4 + (threadIdx.x >> 6);   // one wave per row
    int l = threadIdx.x & 63;
    const float* row = A_log + (size_t)d * 512;
    float s = 0.f;
    for (int k = l; k < 512; k += 64) s += expf(row[k]);
    #pragma unroll
    for (int off = 32; off > 0; off >>= 1) s += __shfl_down(s, off);
    if (l == 0) decay[d] = expf(-s * (1.f / 512.f));  // exp(mean(-exp(A_log)))
}

// ---- chunked scan: S=4096 -> 64 chunks x 64 steps, per (b,n) lane ----
__global__ void scan_partial(const bf16_t* __restrict__ s, const float* __restrict__ decay,
                             float* __restrict__ carry)
{
    int g = blockIdx.x * 256 + threadIdx.x;       // B*N*64 = 131072
    int n = g & 511, ch = (g >> 9) & 63, b = g >> 15;
    float dec = decay[n];
    const bf16_t* sp = s + (size_t)(b * 4096 + ch * 64) * 512 + n;
    float st = 0.f;
    #pragma unroll 8
    for (int i = 0; i < 64; ++i) st = st * dec + (float)sp[(size_t)i * 512];
    carry[(size_t)(b * 64 + ch) * 512 + n] = st;
}

__global__ void scan_carry(const float* __restrict__ carry, const float* __restrict__ decay,
                           const float* __restrict__ state0,
                           float* __restrict__ exc, float* __restrict__ state_f)
{
    int g = blockIdx.x * 256 + threadIdx.x;       // B*N = 2048
    int n = g & 511, b = g >> 9;
    float dec = decay[n];
    float d64 = dec;
    #pragma unroll
    for (int t = 0; t < 6; ++t) d64 *= d64;       // dec^64 via squaring
    float st = state0[g];
    for (int ch = 0; ch < 64; ++ch) {
        size_t idx = (size_t)(b * 64 + ch) * 512 + n;
        exc[idx] = st;                             // exclusive carry-in per chunk
        st = st * d64 + carry[idx];
    }
    state_f[g] = st;                               // final state -> d_out tail
}

__global__ void scan_final(const bf16_t* __restrict__ s, const float* __restrict__ decay,
                           const float* __restrict__ exc, bf16_t* __restrict__ states)
{
    int g = blockIdx.x * 256 + threadIdx.x;       // B*N*64
    int n = g & 511, ch = (g >> 9) & 63, b = g >> 15;
    float dec = decay[n];
    float st = exc[(size_t)(b * 64 + ch) * 512 + n];
    size_t base = (size_t)(b * 4096 + ch * 64) * 512 + n;
    #pragma unroll 8
    for (int i = 0; i < 64; ++i) {
        st = st * dec + (float)s[base + (size_t)i * 512];
        states[base + (size_t)i * 512] = (bf16_t)st;
    }
}

extern "C" void kernel_launch(void* const* d_in, const int* in_sizes, int n_in,
                              void* d_out, int out_size, void* d_ws, size_t ws_size,
                              hipStream_t stream)
{
    const float* x      = (const float*)d_in[0];
    const float* state0 = (const float*)d_in[1];
    const float* W_gate = (const float*)d_in[2];
    const float* b_gate = (const float*)d_in[3];
    const float* W_sp   = (const float*)d_in[4];
    const float* b_sp   = (const float*)d_in[5];
    const float* W_out  = (const float*)d_in[6];
    const float* b_out  = (const float*)d_in[7];
    const float* A_log  = (const float*)d_in[8];
    const float* D_par  = (const float*)d_in[9];
    float* out = (float*)d_out;

    // workspace layout (~51.5 MB)
    char* ws = (char*)d_ws;
    bf16_t* x_bf   = (bf16_t*)ws;                     // 16 MB, reused for states
    bf16_t* states = x_bf;
    bf16_t* xg_bf  = (bf16_t*)(ws + (16u << 20));     // 16 MB
    bf16_t* s_bf   = (bf16_t*)(ws + (32u << 20));     // 16 MB
    bf16_t* Wg_bf  = (bf16_t*)(ws + (48u << 20));     // 5 x 512 KB weights
    bf16_t* Wsp_bf = Wg_bf + 262144;
    bf16_t* Wo_bf  = Wg_bf + 2 * 262144;
    bf16_t* W2_bf  = Wg_bf + 3 * 262144;
    bf16_t* WcT_bf = Wg_bf + 4 * 262144;
    float*  carry  = (float*)(Wg_bf + 5 * 262144);    // 512 KB
    float*  exc    = carry + 131072;                  // 512 KB
    float*  decay  = exc + 131072;                    // 2 KB

    prep_weights<<<dim3(1024), dim3(256), 0, stream>>>(W_gate, W_sp, W_out, D_par,
                                                       Wg_bf, Wsp_bf, Wo_bf, W2_bf);
    compute_decay<<<dim3(128), dim3(256), 0, stream>>>(A_log, decay);
    convert_x<<<dim3(8192), dim3(256), 0, stream>>>((const float4*)x, (bf16x4*)x_bf);

    // WcT[d',n] = sum_d W_out[d',d] * W_sp[n,d]   (grid 8x4 = 32)
    gemm_bt<1><<<dim3(32), dim3(256), 0, stream>>>(
        Wo_bf, Wsp_bf, (const bf16_t*)nullptr, (const bf16_t*)nullptr,
        (const float*)nullptr, (void*)WcT_bf, 512, 512, 1);
    // xg = silu(x W_gate^T + b_gate)   (grid 256x4 = 1024 -> 4 blocks/CU)
    gemm_bt<2><<<dim3(1024), dim3(256), 0, stream>>>(
        x_bf, Wg_bf, (const bf16_t*)nullptr, (const bf16_t*)nullptr,
        b_gate, (void*)xg_bf, 16384, 512, 1);
    // s = xg W_sp^T + b_sp
    gemm_bt<1><<<dim3(1024), dim3(256), 0, stream>>>(
        xg_bf, Wsp_bf, (const bf16_t*)nullptr, (const bf16_t*)nullptr,
        b_sp, (void*)s_bf, 16384, 512, 1);

    scan_partial<<<dim3(512), dim3(256), 0, stream>>>(s_bf, decay, carry);
    scan_carry<<<dim3(8), dim3(256), 0, stream>>>(carry, decay, state0, exc, out + 8388608);
    scan_final<<<dim3(512), dim3(256), 0, stream>>>(s_bf, decay, exc, states);

    // out = states WcT^T + xg W2^T + b_out   (dual-phase accumulate, 32 steps)
    gemm_bt<0><<<dim3(1024), dim3(256), 0, stream>>>(
        states, WcT_bf, xg_bf, W2_bf, b_out, (void*)out, 16384, 512, 2);
}

// Round 3
// 134.702 us; speedup vs baseline: 1.2586x; 1.2586x over previous
//
#include <hip/hip_runtime.h>
#include <hip/hip_bf16.h>
#include <stdint.h>

// SSMBlock: x -> silu(x Wg^T) -> s = xg Wsp^T -> scan(decay) -> out = states WcT^T + xg W2^T + b_out
// R2 GEMM: B-resident. 64-col x 512-K W-panel staged ONCE in LDS (64KB), then a
// barrier-free K-loop: A direct global->VGPR, B via ds_read_b128. K=512 fixed.

typedef __bf16 bf16_t;
typedef bf16_t bf16x8 __attribute__((ext_vector_type(8)));
typedef bf16_t bf16x4 __attribute__((ext_vector_type(4)));
typedef float  f32x4  __attribute__((ext_vector_type(4)));

static __device__ __forceinline__ void async_copy16(bf16_t* lds, const bf16_t* g) {
    __builtin_amdgcn_global_load_lds((const __attribute__((address_space(1))) void*)g,
                                     (__attribute__((address_space(3))) void*)lds, 16, 0, 0);
}

// Block: 512 threads = 8 waves. Tile M=256 (wave w owns rows w*32..w*32+31), N=64.
// LDS Bs element layout [kcomb(64)][col(64)][8]: chunk q holds W[n0 + (q&63)][(q>>6)*8 ..+8].
// Frag reads: 16-lane groups hit contiguous 256B -> no bank conflicts (verified 0 in R0/R1).
// K-loop has NO barriers: A-frag quad {l,l+16,l+32,l+48} covers one 64B line (coalesced),
// fully unrolled 16 steps -> compiler pipelines loads with counted vmcnt.
// MODE: 0 = f32 out (+bias), 1 = bf16 out (+bias), 2 = silu -> bf16 (+bias)
template <int MODE>
__global__ __launch_bounds__(512, 4) void gemm_bres(
    const bf16_t* __restrict__ A0, const bf16_t* __restrict__ W0,
    const bf16_t* __restrict__ A1, const bf16_t* __restrict__ W1,
    const float* __restrict__ bias, void* __restrict__ outp,
    int M, int Nw, int nph)
{
    constexpr int K = 512, NKS = 16;
    __shared__ bf16_t Bs[64 * 512];   // 64 KB
    const int tid = threadIdx.x;
    int bid = blockIdx.x;
    {   // XCD-chunked swizzle: the 8 n-tiles sharing an A-panel land on one XCD's L2
        int nwg = gridDim.x;
        if ((nwg & 7) == 0) bid = (bid & 7) * (nwg >> 3) + (bid >> 3);
    }
    const int tN = Nw >> 6;
    const int m0 = (bid / tN) << 8, n0 = (bid % tN) << 6;
    const int l = tid & 63, w = tid >> 6;
    const int lr = l & 15, kc = l >> 4;

    // bias preload
    float bv[4];
    #pragma unroll
    for (int j = 0; j < 4; ++j)
        bv[j] = bias ? bias[n0 + j * 16 + lr] : 0.f;

    f32x4 acc[2][4];
    const f32x4 z = {0.f, 0.f, 0.f, 0.f};
    #pragma unroll
    for (int i = 0; i < 2; ++i)
        #pragma unroll
        for (int j = 0; j < 4; ++j) acc[i][j] = z;

    for (int ph = 0; ph < nph; ++ph) {
        const bf16_t* __restrict__ Ap = ph ? A1 : A0;
        const bf16_t* __restrict__ Wp = ph ? W1 : W0;
        if (ph) __syncthreads();           // all waves done reading old B-panel
        // stage B-panel: 4096 x 16B chunks, 8 per thread. chunk q = j*512 + w*64 + l:
        // col = l, kcomb = j*8 + w  ->  src = Wp + (n0+l)*K + (j*8+w)*8
        #pragma unroll
        for (int j = 0; j < 8; ++j)
            async_copy16(&Bs[(j * 512 + w * 64) * 8],
                         Wp + (size_t)(n0 + l) * K + (j * 8 + w) * 8);
        __syncthreads();                   // drains vmcnt -> panel ready
        const bf16_t* __restrict__ Arow0 = Ap + (size_t)(m0 + w * 32 + lr) * K + kc * 8;
        const bf16_t* __restrict__ Arow1 = Arow0 + (size_t)16 * K;
        #pragma unroll
        for (int ks = 0; ks < NKS; ++ks) {
            bf16x8 a[2], b[4];
            a[0] = *(const bf16x8*)(Arow0 + ks * 32);
            a[1] = *(const bf16x8*)(Arow1 + ks * 32);
            #pragma unroll
            for (int j = 0; j < 4; ++j)
                b[j] = *(const bf16x8*)(&Bs[((ks * 4 + kc) * 64 + j * 16 + lr) * 8]);
            #pragma unroll
            for (int i = 0; i < 2; ++i)
                #pragma unroll
                for (int j = 0; j < 4; ++j)
                    acc[i][j] = __builtin_amdgcn_mfma_f32_16x16x32_bf16(a[i], b[j], acc[i][j], 0, 0, 0);
        }
    }

    // C/D layout: col = lane&15, row = (lane>>4)*4 + reg
    float*  outF = (float*)outp;
    bf16_t* outB = (bf16_t*)outp;
    #pragma unroll
    for (int i = 0; i < 2; ++i) {
        const int row = m0 + w * 32 + i * 16 + kc * 4;
        #pragma unroll
        for (int j = 0; j < 4; ++j) {
            const int col = n0 + j * 16 + lr;
            #pragma unroll
            for (int r = 0; r < 4; ++r) {
                float v = acc[i][j][r] + bv[j];
                size_t idx = (size_t)(row + r) * Nw + col;
                if (MODE == 0)      outF[idx] = v;
                else if (MODE == 1) outB[idx] = (bf16_t)v;
                else { float sv = v / (1.f + __expf(-v)); outB[idx] = (bf16_t)sv; }
            }
        }
    }
}

// fused prep: x->bf16 (all 8192 blocks), weight prep (blocks<1024), decay (blocks<128)
__global__ void prep_all(const float4* __restrict__ x, bf16x4* __restrict__ xb,
                         const float* __restrict__ Wg, const float* __restrict__ Wsp,
                         const float* __restrict__ Wo, const float* __restrict__ Dp,
                         bf16_t* __restrict__ Wg_bf, bf16_t* __restrict__ Wsp_bf,
                         bf16_t* __restrict__ Wo_bf, bf16_t* __restrict__ W2_bf,
                         const float* __restrict__ A_log, float* __restrict__ decay)
{
    const int blk = blockIdx.x, tid = threadIdx.x;
    {   // x -> bf16, 4 floats/thread
        int i = blk * 256 + tid;
        float4 v = x[i];
        bf16x4 o;
        o[0] = (bf16_t)v.x; o[1] = (bf16_t)v.y; o[2] = (bf16_t)v.z; o[3] = (bf16_t)v.w;
        xb[i] = o;
    }
    if (blk < 1024) {
        int i = blk * 256 + tid;          // 512*512 elements
        Wg_bf[i]  = (bf16_t)Wg[i];
        Wsp_bf[i] = (bf16_t)Wsp[i];
        float wo  = Wo[i];
        Wo_bf[i]  = (bf16_t)wo;
        W2_bf[i]  = (bf16_t)(wo * Dp[i & 511]);   // W2[d',d] = W_out[d',d]*D[d]
    }
    if (blk < 128) {
        int d = blk * 4 + (tid >> 6);     // one wave per row of A_log
        int ll = tid & 63;
        const float* row = A_log + (size_t)d * 512;
        float s = 0.f;
        for (int k = ll; k < 512; k += 64) s += expf(row[k]);
        #pragma unroll
        for (int off = 32; off > 0; off >>= 1) s += __shfl_down(s, off);
        if (ll == 0) decay[d] = expf(-s * (1.f / 512.f));  // exp(mean(-exp(A_log)))
    }
}

// ---- chunked scan: S=4096 -> 64 chunks x 64 steps, per (b,n) lane ----
__global__ void scan_partial(const bf16_t* __restrict__ s, const float* __restrict__ decay,
                             float* __restrict__ carry)
{
    int g = blockIdx.x * 256 + threadIdx.x;       // B*N*64 = 131072
    int n = g & 511, ch = (g >> 9) & 63, b = g >> 15;
    float dec = decay[n];
    const bf16_t* sp = s + (size_t)(b * 4096 + ch * 64) * 512 + n;
    float st = 0.f;
    #pragma unroll 8
    for (int i = 0; i < 64; ++i) st = st * dec + (float)sp[(size_t)i * 512];
    carry[(size_t)(b * 64 + ch) * 512 + n] = st;
}

__global__ void scan_carry(const float* __restrict__ carry, const float* __restrict__ decay,
                           const float* __restrict__ state0,
                           float* __restrict__ exc, float* __restrict__ state_f)
{
    int g = blockIdx.x * 256 + threadIdx.x;       // B*N = 2048
    int n = g & 511, b = g >> 9;
    float dec = decay[n];
    float d64 = dec;
    #pragma unroll
    for (int t = 0; t < 6; ++t) d64 *= d64;       // dec^64 via squaring
    float st = state0[g];
    for (int ch = 0; ch < 64; ++ch) {
        size_t idx = (size_t)(b * 64 + ch) * 512 + n;
        exc[idx] = st;                             // exclusive carry-in per chunk
        st = st * d64 + carry[idx];
    }
    state_f[g] = st;                               // final state -> d_out tail
}

__global__ void scan_final(const bf16_t* __restrict__ s, const float* __restrict__ decay,
                           const float* __restrict__ exc, bf16_t* __restrict__ states)
{
    int g = blockIdx.x * 256 + threadIdx.x;       // B*N*64
    int n = g & 511, ch = (g >> 9) & 63, b = g >> 15;
    float dec = decay[n];
    float st = exc[(size_t)(b * 64 + ch) * 512 + n];
    size_t base = (size_t)(b * 4096 + ch * 64) * 512 + n;
    #pragma unroll 8
    for (int i = 0; i < 64; ++i) {
        st = st * dec + (float)s[base + (size_t)i * 512];
        states[base + (size_t)i * 512] = (bf16_t)st;
    }
}

extern "C" void kernel_launch(void* const* d_in, const int* in_sizes, int n_in,
                              void* d_out, int out_size, void* d_ws, size_t ws_size,
                              hipStream_t stream)
{
    const float* x      = (const float*)d_in[0];
    const float* state0 = (const float*)d_in[1];
    const float* W_gate = (const float*)d_in[2];
    const float* b_gate = (const float*)d_in[3];
    const float* W_sp   = (const float*)d_in[4];
    const float* b_sp   = (const float*)d_in[5];
    const float* W_out  = (const float*)d_in[6];
    const float* b_out  = (const float*)d_in[7];
    const float* A_log  = (const float*)d_in[8];
    const float* D_par  = (const float*)d_in[9];
    float* out = (float*)d_out;

    // workspace layout (~51.5 MB)
    char* ws = (char*)d_ws;
    bf16_t* x_bf   = (bf16_t*)ws;                     // 16 MB, reused for states
    bf16_t* states = x_bf;
    bf16_t* xg_bf  = (bf16_t*)(ws + (16u << 20));     // 16 MB
    bf16_t* s_bf   = (bf16_t*)(ws + (32u << 20));     // 16 MB
    bf16_t* Wg_bf  = (bf16_t*)(ws + (48u << 20));     // 5 x 512 KB weights
    bf16_t* Wsp_bf = Wg_bf + 262144;
    bf16_t* Wo_bf  = Wg_bf + 2 * 262144;
    bf16_t* W2_bf  = Wg_bf + 3 * 262144;
    bf16_t* WcT_bf = Wg_bf + 4 * 262144;
    float*  carry  = (float*)(Wg_bf + 5 * 262144);    // 512 KB
    float*  exc    = carry + 131072;                  // 512 KB
    float*  decay  = exc + 131072;                    // 2 KB

    prep_all<<<dim3(8192), dim3(256), 0, stream>>>(
        (const float4*)x, (bf16x4*)x_bf, W_gate, W_sp, W_out, D_par,
        Wg_bf, Wsp_bf, Wo_bf, W2_bf, A_log, decay);

    // WcT[d',n] = sum_d W_out[d',d] * W_sp[n,d]   (grid 2x8 = 16)
    gemm_bres<1><<<dim3(16), dim3(512), 0, stream>>>(
        Wo_bf, Wsp_bf, (const bf16_t*)nullptr, (const bf16_t*)nullptr,
        (const float*)nullptr, (void*)WcT_bf, 512, 512, 1);
    // xg = silu(x W_gate^T + b_gate)   (grid 64x8 = 512 -> exactly 2 blocks/CU)
    gemm_bres<2><<<dim3(512), dim3(512), 0, stream>>>(
        x_bf, Wg_bf, (const bf16_t*)nullptr, (const bf16_t*)nullptr,
        b_gate, (void*)xg_bf, 16384, 512, 1);
    // s = xg W_sp^T + b_sp
    gemm_bres<1><<<dim3(512), dim3(512), 0, stream>>>(
        xg_bf, Wsp_bf, (const bf16_t*)nullptr, (const bf16_t*)nullptr,
        b_sp, (void*)s_bf, 16384, 512, 1);

    scan_partial<<<dim3(512), dim3(256), 0, stream>>>(s_bf, decay, carry);
    scan_carry<<<dim3(8), dim3(256), 0, stream>>>(carry, decay, state0, exc, out + 8388608);
    scan_final<<<dim3(512), dim3(256), 0, stream>>>(s_bf, decay, exc, states);

    // out = states WcT^T + xg W2^T + b_out   (dual-phase accumulate)
    gemm_bres<0><<<dim3(512), dim3(512), 0, stream>>>(
        states, WcT_bf, xg_bf, W2_bf, b_out, (void*)out, 16384, 512, 2);
}